// Round 5
// baseline (319.747 us; speedup 1.0000x reference)
//
#include <hip/hip_runtime.h>

typedef unsigned short u16;
typedef unsigned int u32;
typedef __attribute__((ext_vector_type(4))) float f32x4;
typedef __attribute__((ext_vector_type(8))) short bf16x8;
typedef __attribute__((ext_vector_type(4))) u16 u16x4;
typedef __attribute__((ext_vector_type(8))) u16 u16x8;

#define B_ 16
#define N_ 1024
#define D_ 1024
#define BM 256
#define BN 256
#define BK 64
#define REGION_BYTES (128 * BK * 2)  // 16 KiB half-tile region

__device__ __forceinline__ float bf2f(u16 v) {
  return __uint_as_float((u32)v << 16);
}
__device__ __forceinline__ u16 f2bf(float f) {
  u32 u = __float_as_uint(f);
  return (u16)((u + 0x7FFFu + ((u >> 16) & 1u)) >> 16);
}
__device__ __forceinline__ void gload_lds16(const void* g, void* l) {
  __builtin_amdgcn_global_load_lds(
      (const __attribute__((address_space(1))) void*)g,
      (__attribute__((address_space(3))) void*)l, 16, 0, 0);
}

// ---------------- cast fp32 -> bf16 (vectorized) ----------------
__global__ __launch_bounds__(256) void cast_kernel(const float* __restrict__ in,
                                                   u16* __restrict__ out, int n4) {
  const int stride = gridDim.x * blockDim.x;
  for (int i = blockIdx.x * blockDim.x + threadIdx.x; i < n4; i += stride) {
    float4 v = ((const float4*)in)[i];
    u16x4 o;
    o[0] = f2bf(v.x); o[1] = f2bf(v.y); o[2] = f2bf(v.z); o[3] = f2bf(v.w);
    ((u16x4*)out)[i] = o;
  }
}

// fused cast of the 4 weight matrices into one contiguous bf16 region
__global__ __launch_bounds__(256) void cast4_kernel(
    const float* __restrict__ w0, const float* __restrict__ w1,
    const float* __restrict__ w2, const float* __restrict__ w3,
    u16* __restrict__ out) {
  const int per = (D_ * D_) / 4;
  const int stride = gridDim.x * blockDim.x;
  for (int i = blockIdx.x * blockDim.x + threadIdx.x; i < 4 * per; i += stride) {
    const int w = i / per, r = i - w * per;
    const float* src = (w == 0) ? w0 : (w == 1) ? w1 : (w == 2) ? w2 : w3;
    float4 v = ((const float4*)src)[r];
    u16x4 o;
    o[0] = f2bf(v.x); o[1] = f2bf(v.y); o[2] = f2bf(v.z); o[3] = f2bf(v.w);
    ((u16x4*)out)[i] = o;
  }
}

// ---------------- 256x256 8-wave 4-phase/K-tile bt-GEMM (m201-style) -------
// C[i,j] = sum_k A[i,k]*B[j,k].  Grid MUST be exactly 256 blocks (1/CU).
// LDS: 2 buf x 4 regions (A0,A1,B0,B1), each 128x64 bf16, XOR-swizzled
// byte^=((r&7)<<4) via pre-swizzled global source + swizzled ds_read.
// Phase = {ds_read subtile + stage half-tile, bar, lgkmcnt(0), 16 MFMA, bar}.
// Stages: P1->HA0(t+1), P2->HA1(t+1), P3->HB0(t+2), P4->HB1(t+2);
// one counted vmcnt(4) gate per tile at end of P4 (never 0 mid-loop).
template <typename OutT>
__global__ __launch_bounds__(512, 2) void gemm_bt256(
    const u16* __restrict__ A, const u16* __restrict__ Bm, OutT* __restrict__ C,
    int K, int ldc, long long sA, long long sB, long long sC,
    int tx_n, int nb_per) {
  __shared__ u16 lds[2][4][128 * BK];  // [buf][A0,A1,B0,B1]
  const int tid = threadIdx.x;
  const int lane = tid & 63;
  const int wid = tid >> 6;
  const int wm = wid >> 2;   // 0..1 -> 128 rows
  const int wn = wid & 3;    // 0..3 -> 64 cols
  const int rl = lane & 15, kl = lane >> 4;

  // bijective XCD swizzle over 256 blocks (8 XCDs x 32-chunk)
  const int orig = blockIdx.x;
  const int wgid = ((orig & 7) << 5) | (orig >> 3);
  const int batch = wgid / nb_per;
  const int rem = wgid % nb_per;
  const int row0 = (rem / tx_n) * BM, col0 = (rem % tx_n) * BN;
  A += (long long)batch * sA;
  Bm += (long long)batch * sB;
  C += (long long)batch * sC;

  auto region = [&](int buf, int rg) -> char* {
    return (char*)&lds[0][0][0] + (size_t)(buf * 4 + rg) * REGION_BYTES;
  };

  // stage one 128x64 half-tile (16 KB): 2 gload_lds/thread, linear LDS dest,
  // inverse-swizzled global source. rg: 0=A0,1=A1,2=B0,3=B1.
  auto stageHalf = [&](const u16* src, int t, int buf, int rg, int grow0) {
    char* base = region(buf, rg);
#pragma unroll
    for (int g = 0; g < 2; ++g) {
      const int d = g * 8192 + tid * 16;
      const int r = d >> 7;
      const int li = (d & 127) ^ ((r & 7) << 4);
      gload_lds16(src + (size_t)(grow0 + r) * K + t * BK + (li >> 1), base + d);
    }
  };
  auto rdA = [&](int buf, int mi, int kk) -> bf16x8 {
    const int R = wm * 128 + mi * 16 + rl;
    const int r = R & 127;
    const int p = (r * 128 + kk * 64 + kl * 16) ^ ((r & 7) << 4);
    return *(const bf16x8*)(region(buf, R >> 7) + p);
  };
  auto rdB = [&](int buf, int ni, int kk) -> bf16x8 {
    const int Rb = wn * 64 + ni * 16 + rl;
    const int r = Rb & 127;
    const int p = (r * 128 + kk * 64 + kl * 16) ^ ((r & 7) << 4);
    return *(const bf16x8*)(region(buf, 2 + (Rb >> 7)) + p);
  };

  f32x4 acc[8][4] = {};
  bf16x8 aF[4][2], bF[2][2], bG[2][2];

  // prologue: tile0 all 4 halves + tile1 B halves (HA(1) staged in P1/P2(0))
  stageHalf(A, 0, 0, 0, row0);  stageHalf(A, 0, 0, 1, row0 + 128);
  stageHalf(Bm, 0, 0, 2, col0); stageHalf(Bm, 0, 0, 3, col0 + 128);
  stageHalf(Bm, 1, 1, 2, col0); stageHalf(Bm, 1, 1, 3, col0 + 128);
  asm volatile("s_waitcnt vmcnt(4)" ::: "memory");
  __builtin_amdgcn_s_barrier();

  const int nt = K / BK;
  for (int t = 0; t < nt; ++t) {
    const int cur = t & 1;
    // ---- P1: read A-sub0 (8) + B-sub0 (4); stage HA0(t+1); MFMA Q00 ----
#pragma unroll
    for (int mi = 0; mi < 4; ++mi) {
      aF[mi][0] = rdA(cur, mi, 0); aF[mi][1] = rdA(cur, mi, 1);
    }
#pragma unroll
    for (int ni = 0; ni < 2; ++ni) {
      bF[ni][0] = rdB(cur, ni, 0); bF[ni][1] = rdB(cur, ni, 1);
    }
    if (t + 1 < nt) stageHalf(A, t + 1, cur ^ 1, 0, row0);
    asm volatile("s_waitcnt lgkmcnt(8)" ::: "memory");
    __builtin_amdgcn_sched_barrier(0);
    __builtin_amdgcn_s_barrier();
    asm volatile("s_waitcnt lgkmcnt(0)" ::: "memory");
    __builtin_amdgcn_sched_barrier(0);
    __builtin_amdgcn_s_setprio(1);
#pragma unroll
    for (int kk = 0; kk < 2; ++kk)
#pragma unroll
      for (int mi = 0; mi < 4; ++mi)
#pragma unroll
        for (int ni = 0; ni < 2; ++ni)
          acc[mi][ni] = __builtin_amdgcn_mfma_f32_16x16x32_bf16(
              aF[mi][kk], bF[ni][kk], acc[mi][ni], 0, 0, 0);
    __builtin_amdgcn_s_setprio(0);
    __builtin_amdgcn_sched_barrier(0);
    __builtin_amdgcn_s_barrier();
    // ---- P2: read B-sub1 (4); stage HA1(t+1); MFMA Q01 ----
#pragma unroll
    for (int ni = 0; ni < 2; ++ni) {
      bG[ni][0] = rdB(cur, 2 + ni, 0); bG[ni][1] = rdB(cur, 2 + ni, 1);
    }
    if (t + 1 < nt) stageHalf(A, t + 1, cur ^ 1, 1, row0 + 128);
    __builtin_amdgcn_sched_barrier(0);
    __builtin_amdgcn_s_barrier();
    asm volatile("s_waitcnt lgkmcnt(0)" ::: "memory");
    __builtin_amdgcn_sched_barrier(0);
    __builtin_amdgcn_s_setprio(1);
#pragma unroll
    for (int kk = 0; kk < 2; ++kk)
#pragma unroll
      for (int mi = 0; mi < 4; ++mi)
#pragma unroll
        for (int ni = 0; ni < 2; ++ni)
          acc[mi][2 + ni] = __builtin_amdgcn_mfma_f32_16x16x32_bf16(
              aF[mi][kk], bG[ni][kk], acc[mi][2 + ni], 0, 0, 0);
    __builtin_amdgcn_s_setprio(0);
    __builtin_amdgcn_sched_barrier(0);
    __builtin_amdgcn_s_barrier();
    // ---- P3: read A-sub1 (8); stage HB0(t+2) (B(cur) freed at P2); Q11 ----
#pragma unroll
    for (int mi = 0; mi < 4; ++mi) {
      aF[mi][0] = rdA(cur, 4 + mi, 0); aF[mi][1] = rdA(cur, 4 + mi, 1);
    }
    if (t + 2 < nt) stageHalf(Bm, t + 2, cur, 2, col0);
    __builtin_amdgcn_sched_barrier(0);
    __builtin_amdgcn_s_barrier();
    asm volatile("s_waitcnt lgkmcnt(0)" ::: "memory");
    __builtin_amdgcn_sched_barrier(0);
    __builtin_amdgcn_s_setprio(1);
#pragma unroll
    for (int kk = 0; kk < 2; ++kk)
#pragma unroll
      for (int mi = 0; mi < 4; ++mi)
#pragma unroll
        for (int ni = 0; ni < 2; ++ni)
          acc[4 + mi][2 + ni] = __builtin_amdgcn_mfma_f32_16x16x32_bf16(
              aF[mi][kk], bG[ni][kk], acc[4 + mi][2 + ni], 0, 0, 0);
    __builtin_amdgcn_s_setprio(0);
    __builtin_amdgcn_sched_barrier(0);
    __builtin_amdgcn_s_barrier();
    // ---- P4: no reads; stage HB1(t+2); MFMA Q10; counted vmcnt gate ----
    if (t + 2 < nt) stageHalf(Bm, t + 2, cur, 3, col0 + 128);
    __builtin_amdgcn_sched_barrier(0);
    __builtin_amdgcn_s_setprio(1);
#pragma unroll
    for (int kk = 0; kk < 2; ++kk)
#pragma unroll
      for (int mi = 0; mi < 4; ++mi)
#pragma unroll
        for (int ni = 0; ni < 2; ++ni)
          acc[4 + mi][ni] = __builtin_amdgcn_mfma_f32_16x16x32_bf16(
              aF[mi][kk], bF[ni][kk], acc[4 + mi][ni], 0, 0, 0);
    __builtin_amdgcn_s_setprio(0);
    __builtin_amdgcn_sched_barrier(0);
    // gate: tile t+1's HA (staged P1/P2(t)) must be landed; HB(t+2)'s 4
    // loads may stay in flight.
    if (t + 2 < nt)      asm volatile("s_waitcnt vmcnt(4)" ::: "memory");
    else if (t + 1 < nt) asm volatile("s_waitcnt vmcnt(0)" ::: "memory");
    if (t + 1 < nt) __builtin_amdgcn_s_barrier();
  }
  // epilogue: C/D map col=lane&15, row=(lane>>4)*4+j
#pragma unroll
  for (int mi = 0; mi < 8; ++mi)
#pragma unroll
    for (int ni = 0; ni < 4; ++ni)
#pragma unroll
      for (int j = 0; j < 4; ++j) {
        const int rr = row0 + wm * 128 + mi * 16 + kl * 4 + j;
        const int cc = col0 + wn * 64 + ni * 16 + rl;
        const float v = acc[mi][ni][j];
        if constexpr (sizeof(OutT) == 2)
          C[(size_t)rr * ldc + cc] = (OutT)f2bf(v);
        else
          C[(size_t)rr * ldc + cc] = v;
      }
}

// ---------------- key: softmax over d (rows), write transposed KT[b,d,n] ----------------
__global__ __launch_bounds__(256) void key_sm_t(const u16* __restrict__ Kp,
                                                u16* __restrict__ KT) {
  const int b = blockIdx.y, n0 = blockIdx.x * 64;
  const int tid = threadIdx.x, lane = tid & 63, w = tid >> 6;
  __shared__ float smax[64], sinv[64];
  __shared__ u16 Tl[64][72];
  const u16* base = Kp + ((size_t)b * N_ + n0) * D_;
  for (int i = 0; i < 16; ++i) {
    const int r = w * 16 + i;
    const u16x8* rp = (const u16x8*)(base + (size_t)r * D_ + lane * 16);
    u16x8 v0 = rp[0], v1 = rp[1];
    float f[16];
#pragma unroll
    for (int j = 0; j < 8; ++j) { f[j] = bf2f(v0[j]); f[8 + j] = bf2f(v1[j]); }
    float m = -1e30f;
#pragma unroll
    for (int j = 0; j < 16; ++j) m = fmaxf(m, f[j]);
    for (int off = 32; off; off >>= 1) m = fmaxf(m, __shfl_xor(m, off));
    float s = 0.f;
#pragma unroll
    for (int j = 0; j < 16; ++j) s += __expf(f[j] - m);
    for (int off = 32; off; off >>= 1) s += __shfl_xor(s, off);
    if (lane == 0) { smax[r] = m; sinv[r] = 1.f / s; }
  }
  __syncthreads();
  for (int ct = 0; ct < 16; ++ct) {
    const int r = tid >> 2, cb = (tid & 3) * 16;
    const u16x8* rp = (const u16x8*)(base + (size_t)r * D_ + ct * 64 + cb);
    u16x8 v0 = rp[0], v1 = rp[1];
    const float m = smax[r], inv = sinv[r];
#pragma unroll
    for (int j = 0; j < 8; ++j) {
      Tl[r][cb + j] = f2bf(__expf(bf2f(v0[j]) - m) * inv);
      Tl[r][cb + 8 + j] = f2bf(__expf(bf2f(v1[j]) - m) * inv);
    }
    __syncthreads();
    const int c = tid >> 2, nb = (tid & 3) * 16;
    u16x8 o0, o1;
#pragma unroll
    for (int e = 0; e < 8; ++e) { o0[e] = Tl[nb + e][c]; o1[e] = Tl[nb + 8 + e][c]; }
    u16x8* op = (u16x8*)(KT + ((size_t)b * D_ + ct * 64 + c) * N_ + n0 + nb);
    op[0] = o0; op[1] = o1;
    __syncthreads();
  }
}

// ---------------- query: softmax over n (cols), write transposed QT[b,d,n] ----------------
__global__ __launch_bounds__(256) void query_sm_t(const u16* __restrict__ Qp,
                                                  u16* __restrict__ QT) {
  const int b = blockIdx.y, d0 = blockIdx.x * 64;
  const int tid = threadIdx.x, l = tid & 63, g = tid >> 6;
  __shared__ float pm[4][64], ps[4][64];
  __shared__ float cmax[64], cinv[64];
  __shared__ u16 Tl[64][72];
  const u16* base = Qp + (size_t)b * N_ * D_;
  float m = -1e30f, s = 0.f;
  for (int n = g * 256; n < g * 256 + 256; ++n) {
    const float x = bf2f(base[(size_t)n * D_ + d0 + l]);
    const float nm = fmaxf(m, x);
    s = s * __expf(m - nm) + __expf(x - nm);
    m = nm;
  }
  pm[g][l] = m; ps[g][l] = s;
  __syncthreads();
  if (tid < 64) {
    float M = pm[0][tid];
    for (int k2 = 1; k2 < 4; ++k2) M = fmaxf(M, pm[k2][tid]);
    float S = 0.f;
    for (int k2 = 0; k2 < 4; ++k2) S += ps[k2][tid] * __expf(pm[k2][tid] - M);
    cmax[tid] = M; cinv[tid] = 1.f / S;
  }
  __syncthreads();
  for (int nt = 0; nt < 16; ++nt) {
    const int r = tid >> 2, cb = (tid & 3) * 16;
    const u16x8* rp = (const u16x8*)(base + (size_t)(nt * 64 + r) * D_ + d0 + cb);
    u16x8 v0 = rp[0], v1 = rp[1];
#pragma unroll
    for (int j = 0; j < 8; ++j) {
      Tl[r][cb + j] = f2bf(__expf(bf2f(v0[j]) - cmax[cb + j]) * cinv[cb + j]);
      Tl[r][cb + 8 + j] =
          f2bf(__expf(bf2f(v1[j]) - cmax[cb + 8 + j]) * cinv[cb + 8 + j]);
    }
    __syncthreads();
    const int c = tid >> 2, nb = (tid & 3) * 16;
    u16x8 o0, o1;
#pragma unroll
    for (int e = 0; e < 8; ++e) { o0[e] = Tl[nb + e][c]; o1[e] = Tl[nb + 8 + e][c]; }
    u16x8* op = (u16x8*)(QT + ((size_t)b * D_ + d0 + c) * N_ + nt * 64 + nb);
    op[0] = o0; op[1] = o1;
    __syncthreads();
  }
}

extern "C" void kernel_launch(void* const* d_in, const int* in_sizes, int n_in,
                              void* d_out, int out_size, void* d_ws, size_t ws_size,
                              hipStream_t stream) {
  const float* x = (const float*)d_in[0];
  const float* Wk = (const float*)d_in[1];
  const float* Wq = (const float*)d_in[2];
  const float* Wv = (const float*)d_in[3];
  const float* Wr = (const float*)d_in[4];
  float* out = (float*)d_out;
  char* ws = (char*)d_ws;
  const size_t MB = 1ull << 20;

  u16* Xb  = (u16*)(ws + 0 * MB);
  u16* KT  = (u16*)(ws + 0 * MB);
  u16* Wkb = (u16*)(ws + 32 * MB);
  u16* Wqb = (u16*)(ws + 34 * MB);
  u16* Wvb = (u16*)(ws + 36 * MB);
  u16* Wrb = (u16*)(ws + 38 * MB);
  u16* Kp  = (u16*)(ws + 40 * MB);
  u16* St  = (u16*)(ws + 40 * MB);
  u16* Qp  = (u16*)(ws + 72 * MB);
  u16* Att = (u16*)(ws + 72 * MB);
  u16* V   = (u16*)(ws + 104 * MB);
  u16* QT  = (u16*)(ws + 136 * MB);

  const int nX = B_ * N_ * D_;
  cast_kernel<<<2048, 256, 0, stream>>>(x, Xb, nX / 4);
  cast4_kernel<<<1024, 256, 0, stream>>>(Wk, Wq, Wv, Wr, Wkb);

  // projections: (16384 x 1024) = Xb @ W^T   -> 64x4 tiles = 256 blocks
  gemm_bt256<u16><<<256, 512, 0, stream>>>(Xb, Wkb, Kp, D_, D_, 0, 0, 0, 4, 256);
  gemm_bt256<u16><<<256, 512, 0, stream>>>(Xb, Wqb, Qp, D_, D_, 0, 0, 0, 4, 256);
  gemm_bt256<u16><<<256, 512, 0, stream>>>(Xb, Wvb, V, D_, D_, 0, 0, 0, 4, 256);

  key_sm_t<<<dim3(N_ / 64, B_), 256, 0, stream>>>(Kp, KT);
  query_sm_t<<<dim3(D_ / 64, B_), 256, 0, stream>>>(Qp, QT);

  const long long sNN = (long long)N_ * D_;
  // St[b,d',d] = sum_n QT[b,d',n]*KT[b,d,n]: 16 batches x (4x4) = 256 blocks
  gemm_bt256<u16><<<256, 512, 0, stream>>>(QT, KT, St, N_, D_, sNN, sNN, sNN, 4, 16);
  // Att[b,m,d'] = sum_d V[b,m,d]*St[b,d',d]
  gemm_bt256<u16><<<256, 512, 0, stream>>>(V, St, Att, D_, D_, sNN, sNN, sNN, 4, 16);
  // out = Att @ Wr^T (fp32 epilogue)
  gemm_bt256<float><<<256, 512, 0, stream>>>(Att, Wrb, out, D_, D_, 0, 0, 0, 4, 256);
}

// Round 6
// 295.899 us; speedup vs baseline: 1.0806x; 1.0806x over previous
//
#include <hip/hip_runtime.h>

typedef unsigned short u16;
typedef unsigned int u32;
typedef __attribute__((ext_vector_type(4))) float f32x4;
typedef __attribute__((ext_vector_type(8))) short bf16x8;
typedef __attribute__((ext_vector_type(4))) u16 u16x4;
typedef __attribute__((ext_vector_type(8))) u16 u16x8;

#define B_ 16
#define N_ 1024
#define D_ 1024
#define BM 256
#define BN 256
#define BK 64

__device__ __forceinline__ float bf2f(u16 v) {
  return __uint_as_float((u32)v << 16);
}
__device__ __forceinline__ u16 f2bf(float f) {
  u32 u = __float_as_uint(f);
  return (u16)((u + 0x7FFFu + ((u >> 16) & 1u)) >> 16);
}
__device__ __forceinline__ void gload_lds16(const void* g, void* l) {
  __builtin_amdgcn_global_load_lds(
      (const __attribute__((address_space(1))) void*)g,
      (__attribute__((address_space(3))) void*)l, 16, 0, 0);
}

// ---------------- cast fp32 -> bf16 (vectorized) ----------------
__global__ __launch_bounds__(256) void cast_kernel(const float* __restrict__ in,
                                                   u16* __restrict__ out, int n4) {
  const int stride = gridDim.x * blockDim.x;
  for (int i = blockIdx.x * blockDim.x + threadIdx.x; i < n4; i += stride) {
    float4 v = ((const float4*)in)[i];
    u16x4 o;
    o[0] = f2bf(v.x); o[1] = f2bf(v.y); o[2] = f2bf(v.z); o[3] = f2bf(v.w);
    ((u16x4*)out)[i] = o;
  }
}

// fused cast of the 4 weight matrices into one contiguous bf16 region
__global__ __launch_bounds__(256) void cast4_kernel(
    const float* __restrict__ w0, const float* __restrict__ w1,
    const float* __restrict__ w2, const float* __restrict__ w3,
    u16* __restrict__ out) {
  const int per = (D_ * D_) / 4;
  const int stride = gridDim.x * blockDim.x;
  for (int i = blockIdx.x * blockDim.x + threadIdx.x; i < 4 * per; i += stride) {
    const int w = i / per, r = i - w * per;
    const float* src = (w == 0) ? w0 : (w == 1) ? w1 : (w == 2) ? w2 : w3;
    float4 v = ((const float4*)src)[r];
    u16x4 o;
    o[0] = f2bf(v.x); o[1] = f2bf(v.y); o[2] = f2bf(v.z); o[3] = f2bf(v.w);
    ((u16x4*)out)[i] = o;
  }
}

// ---------------- 256x256 8-wave 8-phase/2-tile bt-GEMM (m201 port) --------
// C[i,j] = sum_k A[i,k]*B[j,k], K fixed = 1024 (nt = 16 K-tiles of BK=64).
// LDS [region A0,A1,B0,B1][buf 0,1][128x64 bf16] = 128 KiB. Swizzle
// byte^=((row&7)<<4) via inverse-swizzled global src + swizzled read base.
// 2 K-tiles per loop iter -> all buf indices compile-time; ds_read =
// per-lane base VGPR + imm offset (zero loop VALU).
// Ledger: HA(T+1) staged P1/P2(T) -> buf^1 (read in T-1, drained by phase
// barriers); HB(T+2) staged P3/P4(T) -> buf (B freed after P2(T)). Gate
// vmcnt(4) once per tile at P4 (HB(T+2) in flight); tail: vmcnt(0) at T=14,
// none at T=15.
template <typename OutT, bool SPLITC>
__global__ __launch_bounds__(512, 2) void gemm_bt256(
    const u16* __restrict__ A, const u16* __restrict__ Bm, OutT* __restrict__ C,
    long long sA, long long sB, long long sC, int tx_n, int nb_per) {
  __shared__ u16 lds[4][2][128 * 64];
  const int tid = threadIdx.x;
  const int lane = tid & 63;
  const int wid = tid >> 6;
  const int wm = wid >> 2;   // 0..1 -> 128-row half
  const int wn = wid & 3;    // 0..3 -> 64-col group
  const int rl = lane & 15, kl = lane >> 4;

  // bijective XCD swizzle (nwg % 8 == 0 for all our grids)
  const int nwg = gridDim.x;
  const int orig = blockIdx.x;
  const int wgid = (orig & 7) * (nwg >> 3) + (orig >> 3);
  const int batch = wgid / nb_per;
  const int rem = wgid % nb_per;
  const int row0 = (rem / tx_n) * BM;
  const int col0 = (rem % tx_n) * BN;
  A += (long long)batch * sA;
  Bm += (long long)batch * sB;
  OutT* Cb;
  if constexpr (SPLITC) {
    // merged projections: route by which 1024-col slab; slabs are 32MB apart
    Cb = C + (size_t)(col0 >> 10) * ((size_t)16384 * 1024) + (col0 & 1023);
  } else {
    Cb = C + (long long)batch * sC + col0;
  }

  const char* lb = (const char*)&lds[0][0][0];
  char* lw = (char*)&lds[0][0][0];

  // per-lane swizzled ds_read bases (kk toggles bit 6)
  const u32 swz = (u32)((kl * 16) ^ ((rl & 7) << 4));
  const u32 vA0 = (u32)(wm * 32768 + rl * 128) + swz;
  const u32 vA1 = vA0 ^ 64u;
  const u32 vB0 = (u32)((2 + (wn >> 1)) * 32768 + (wn & 1) * 8192 + rl * 128) + swz;
  const u32 vB1 = vB0 ^ 64u;
#define RDA(BUF, MI, KK) \
  (*(const bf16x8*)(lb + ((KK) ? vA1 : vA0) + ((BUF) * 16384 + (MI) * 2048)))
#define RDB(BUF, NI, KK) \
  (*(const bf16x8*)(lb + ((KK) ? vB1 : vB0) + ((BUF) * 16384 + (NI) * 2048)))

  // per-thread staging bases (inverse-swizzled global source, linear LDS dest)
  const int r0 = tid >> 3;
  const u32 li0 = (u32)(((tid & 7) * 16) ^ ((r0 & 7) << 4));
  const u16* gA0 = A + (size_t)(row0 + r0) * 1024 + (li0 >> 1);
  const u16* gB0 = Bm + (size_t)(col0 + r0) * 1024 + (li0 >> 1);
#define STAGE_A(H, BUF, T)                                                    \
  do {                                                                        \
    gload_lds16(gA0 + (size_t)((H)*128 + 0) * 1024 + (T)*64,                  \
                lw + (H)*32768 + (BUF)*16384 + tid * 16);                     \
    gload_lds16(gA0 + (size_t)((H)*128 + 64) * 1024 + (T)*64,                 \
                lw + (H)*32768 + (BUF)*16384 + 8192 + tid * 16);              \
  } while (0)
#define STAGE_B(H, BUF, T)                                                    \
  do {                                                                        \
    gload_lds16(gB0 + (size_t)((H)*128 + 0) * 1024 + (T)*64,                  \
                lw + (2 + (H)) * 32768 + (BUF)*16384 + tid * 16);             \
    gload_lds16(gB0 + (size_t)((H)*128 + 64) * 1024 + (T)*64,                 \
                lw + (2 + (H)) * 32768 + (BUF)*16384 + 8192 + tid * 16);      \
  } while (0)

  f32x4 acc[8][4] = {};
  bf16x8 aF[4][2], bF[2][2], bG[2][2];

  auto mfma16 = [&](int rb, int cb, bf16x8 (&bb)[2][2]) {
#pragma unroll
    for (int kk = 0; kk < 2; ++kk)
#pragma unroll
      for (int mi = 0; mi < 4; ++mi)
#pragma unroll
        for (int ni = 0; ni < 2; ++ni)
          acc[rb + mi][cb + ni] = __builtin_amdgcn_mfma_f32_16x16x32_bf16(
              aF[mi][kk], bb[ni][kk], acc[rb + mi][cb + ni], 0, 0, 0);
  };

#define SBAR() __builtin_amdgcn_sched_barrier(0)
#define BAR() __builtin_amdgcn_s_barrier()
  // GATE: 0 = vmcnt(4)+bar, 1 = vmcnt(0)+bar, 2 = none
#define TILE(T, BUF, OBUF, STHA, STHB, GATE)                                  \
  {                                                                           \
    /* P1: A-sub0 (8) + B-lo (4) reads; stage HA0(T+1) */                     \
    _Pragma("unroll") for (int mi = 0; mi < 4; ++mi) {                        \
      aF[mi][0] = RDA(BUF, mi, 0); aF[mi][1] = RDA(BUF, mi, 1);               \
    }                                                                         \
    _Pragma("unroll") for (int ni = 0; ni < 2; ++ni) {                        \
      bF[ni][0] = RDB(BUF, ni, 0); bF[ni][1] = RDB(BUF, ni, 1);               \
    }                                                                         \
    if (STHA) STAGE_A(0, OBUF, (T) + 1);                                      \
    asm volatile("s_waitcnt lgkmcnt(8)" ::: "memory");                        \
    SBAR(); BAR();                                                            \
    __builtin_amdgcn_s_setprio(1);                                            \
    mfma16(0, 0, bF);                                                         \
    __builtin_amdgcn_s_setprio(0);                                            \
    SBAR(); BAR();                                                            \
    /* P2: B-hi (4) reads; stage HA1(T+1) */                                  \
    _Pragma("unroll") for (int ni = 0; ni < 2; ++ni) {                        \
      bG[ni][0] = RDB(BUF, 2 + ni, 0); bG[ni][1] = RDB(BUF, 2 + ni, 1);       \
    }                                                                         \
    if (STHA) STAGE_A(1, OBUF, (T) + 1);                                      \
    SBAR(); BAR();                                                            \
    __builtin_amdgcn_s_setprio(1);                                            \
    mfma16(0, 2, bG);                                                         \
    __builtin_amdgcn_s_setprio(0);                                            \
    SBAR(); BAR();                                                            \
    /* P3: A-sub1 (8) reads; stage HB0(T+2) into BUF (B freed after P2) */    \
    _Pragma("unroll") for (int mi = 0; mi < 4; ++mi) {                        \
      aF[mi][0] = RDA(BUF, 4 + mi, 0); aF[mi][1] = RDA(BUF, 4 + mi, 1);       \
    }                                                                         \
    if (STHB) STAGE_B(0, BUF, (T) + 2);                                       \
    SBAR(); BAR();                                                            \
    __builtin_amdgcn_s_setprio(1);                                            \
    mfma16(4, 2, bG);                                                         \
    __builtin_amdgcn_s_setprio(0);                                            \
    SBAR(); BAR();                                                            \
    /* P4: stage HB1(T+2); MFMA; counted gate */                              \
    if (STHB) STAGE_B(1, BUF, (T) + 2);                                       \
    __builtin_amdgcn_s_setprio(1);                                            \
    mfma16(4, 0, bF);                                                         \
    __builtin_amdgcn_s_setprio(0);                                            \
    SBAR();                                                                   \
    if ((GATE) == 0) asm volatile("s_waitcnt vmcnt(4)" ::: "memory");         \
    else if ((GATE) == 1) asm volatile("s_waitcnt vmcnt(0)" ::: "memory");    \
    if ((GATE) != 2) BAR();                                                   \
  }

  // prologue: A(0),B(0) -> buf0; B(1) -> buf1 (12 loads); gate first 8
  STAGE_A(0, 0, 0); STAGE_A(1, 0, 0);
  STAGE_B(0, 0, 0); STAGE_B(1, 0, 0);
  STAGE_B(0, 1, 1); STAGE_B(1, 1, 1);
  asm volatile("s_waitcnt vmcnt(4)" ::: "memory");
  BAR();

#pragma unroll 1
  for (int u = 0; u < 7; ++u) {
    const int T0 = 2 * u;
    TILE(T0, 0, 1, 1, 1, 0);
    TILE(T0 + 1, 1, 0, 1, 1, 0);
  }
  TILE(14, 0, 1, 1, 0, 1);   // stage HA(15) only; drain to 0
  TILE(15, 1, 0, 0, 0, 2);   // final tile: no stages, no gate

#undef TILE
#undef SBAR
#undef BAR
#undef RDA
#undef RDB
#undef STAGE_A
#undef STAGE_B

  // epilogue: C/D map col=lane&15, row=(lane>>4)*4+j
#pragma unroll
  for (int mi = 0; mi < 8; ++mi)
#pragma unroll
    for (int ni = 0; ni < 4; ++ni)
#pragma unroll
      for (int j = 0; j < 4; ++j) {
        const int rr = row0 + wm * 128 + mi * 16 + kl * 4 + j;
        const int cc = wn * 64 + ni * 16 + rl;
        const float v = acc[mi][ni][j];
        if constexpr (sizeof(OutT) == 2)
          Cb[(size_t)rr * 1024 + cc] = (OutT)f2bf(v);
        else
          Cb[(size_t)rr * 1024 + cc] = v;
      }
}

// ---------------- key: softmax over d (rows), write transposed KT[b,d,n] ----------------
__global__ __launch_bounds__(256) void key_sm_t(const u16* __restrict__ Kp,
                                                u16* __restrict__ KT) {
  const int b = blockIdx.y, n0 = blockIdx.x * 64;
  const int tid = threadIdx.x, lane = tid & 63, w = tid >> 6;
  __shared__ float smax[64], sinv[64];
  __shared__ u16 Tl[64][72];
  const u16* base = Kp + ((size_t)b * N_ + n0) * D_;
  for (int i = 0; i < 16; ++i) {
    const int r = w * 16 + i;
    const u16x8* rp = (const u16x8*)(base + (size_t)r * D_ + lane * 16);
    u16x8 v0 = rp[0], v1 = rp[1];
    float f[16];
#pragma unroll
    for (int j = 0; j < 8; ++j) { f[j] = bf2f(v0[j]); f[8 + j] = bf2f(v1[j]); }
    float m = -1e30f;
#pragma unroll
    for (int j = 0; j < 16; ++j) m = fmaxf(m, f[j]);
    for (int off = 32; off; off >>= 1) m = fmaxf(m, __shfl_xor(m, off));
    float s = 0.f;
#pragma unroll
    for (int j = 0; j < 16; ++j) s += __expf(f[j] - m);
    for (int off = 32; off; off >>= 1) s += __shfl_xor(s, off);
    if (lane == 0) { smax[r] = m; sinv[r] = 1.f / s; }
  }
  __syncthreads();
  for (int ct = 0; ct < 16; ++ct) {
    const int r = tid >> 2, cb = (tid & 3) * 16;
    const u16x8* rp = (const u16x8*)(base + (size_t)r * D_ + ct * 64 + cb);
    u16x8 v0 = rp[0], v1 = rp[1];
    const float m = smax[r], inv = sinv[r];
#pragma unroll
    for (int j = 0; j < 8; ++j) {
      Tl[r][cb + j] = f2bf(__expf(bf2f(v0[j]) - m) * inv);
      Tl[r][cb + 8 + j] = f2bf(__expf(bf2f(v1[j]) - m) * inv);
    }
    __syncthreads();
    const int c = tid >> 2, nb = (tid & 3) * 16;
    u16x8 o0, o1;
#pragma unroll
    for (int e = 0; e < 8; ++e) { o0[e] = Tl[nb + e][c]; o1[e] = Tl[nb + 8 + e][c]; }
    u16x8* op = (u16x8*)(KT + ((size_t)b * D_ + ct * 64 + c) * N_ + n0 + nb);
    op[0] = o0; op[1] = o1;
    __syncthreads();
  }
}

// ---------------- query: softmax over n (cols), write transposed QT[b,d,n] ----------------
__global__ __launch_bounds__(256) void query_sm_t(const u16* __restrict__ Qp,
                                                  u16* __restrict__ QT) {
  const int b = blockIdx.y, d0 = blockIdx.x * 64;
  const int tid = threadIdx.x, l = tid & 63, g = tid >> 6;
  __shared__ float pm[4][64], ps[4][64];
  __shared__ float cmax[64], cinv[64];
  __shared__ u16 Tl[64][72];
  const u16* base = Qp + (size_t)b * N_ * D_;
  float m = -1e30f, s = 0.f;
  for (int n = g * 256; n < g * 256 + 256; ++n) {
    const float x = bf2f(base[(size_t)n * D_ + d0 + l]);
    const float nm = fmaxf(m, x);
    s = s * __expf(m - nm) + __expf(x - nm);
    m = nm;
  }
  pm[g][l] = m; ps[g][l] = s;
  __syncthreads();
  if (tid < 64) {
    float M = pm[0][tid];
    for (int k2 = 1; k2 < 4; ++k2) M = fmaxf(M, pm[k2][tid]);
    float S = 0.f;
    for (int k2 = 0; k2 < 4; ++k2) S += ps[k2][tid] * __expf(pm[k2][tid] - M);
    cmax[tid] = M; cinv[tid] = 1.f / S;
  }
  __syncthreads();
  for (int nt = 0; nt < 16; ++nt) {
    const int r = tid >> 2, cb = (tid & 3) * 16;
    const u16x8* rp = (const u16x8*)(base + (size_t)(nt * 64 + r) * D_ + d0 + cb);
    u16x8 v0 = rp[0], v1 = rp[1];
#pragma unroll
    for (int j = 0; j < 8; ++j) {
      Tl[r][cb + j] = f2bf(__expf(bf2f(v0[j]) - cmax[cb + j]) * cinv[cb + j]);
      Tl[r][cb + 8 + j] =
          f2bf(__expf(bf2f(v1[j]) - cmax[cb + 8 + j]) * cinv[cb + 8 + j]);
    }
    __syncthreads();
    const int c = tid >> 2, nb = (tid & 3) * 16;
    u16x8 o0, o1;
#pragma unroll
    for (int e = 0; e < 8; ++e) { o0[e] = Tl[nb + e][c]; o1[e] = Tl[nb + 8 + e][c]; }
    u16x8* op = (u16x8*)(QT + ((size_t)b * D_ + d0 + c) * N_ + nt * 64 + nb);
    op[0] = o0; op[1] = o1;
    __syncthreads();
  }
}

extern "C" void kernel_launch(void* const* d_in, const int* in_sizes, int n_in,
                              void* d_out, int out_size, void* d_ws, size_t ws_size,
                              hipStream_t stream) {
  const float* x = (const float*)d_in[0];
  const float* Wk = (const float*)d_in[1];
  const float* Wq = (const float*)d_in[2];
  const float* Wv = (const float*)d_in[3];
  const float* Wr = (const float*)d_in[4];
  float* out = (float*)d_out;
  char* ws = (char*)d_ws;
  const size_t MB = 1ull << 20;

  u16* Xb  = (u16*)(ws + 0 * MB);
  u16* KT  = (u16*)(ws + 0 * MB);
  u16* Wkb = (u16*)(ws + 32 * MB);   // [Wk;Wq;Wv;Wr] contiguous, 3072+1024 rows
  u16* Wrb = (u16*)(ws + 38 * MB);
  u16* Kp  = (u16*)(ws + 40 * MB);   // Kp/Qp/V each 32 MB apart (SPLITC routing)
  u16* St  = (u16*)(ws + 40 * MB);
  u16* Qp  = (u16*)(ws + 72 * MB);
  u16* Att = (u16*)(ws + 72 * MB);
  u16* V   = (u16*)(ws + 104 * MB);
  u16* QT  = (u16*)(ws + 136 * MB);

  const int nX = B_ * N_ * D_;
  cast_kernel<<<2048, 256, 0, stream>>>(x, Xb, nX / 4);
  cast4_kernel<<<1024, 256, 0, stream>>>(Wk, Wq, Wv, Wr, Wkb);

  // merged projections: (16384 x 3072) = Xb @ [Wk;Wq;Wv]^T -> 64x12 = 768 blocks
  gemm_bt256<u16, true><<<768, 512, 0, stream>>>(Xb, Wkb, Kp, 0, 0, 0, 12, 768);

  key_sm_t<<<dim3(N_ / 64, B_), 256, 0, stream>>>(Kp, KT);
  query_sm_t<<<dim3(D_ / 64, B_), 256, 0, stream>>>(Qp, QT);

  const long long sNN = (long long)N_ * D_;
  // St[b,d',d] = sum_n QT[b,d',n]*KT[b,d,n]: 16 batches x (4x4) = 256 blocks
  gemm_bt256<u16, false><<<256, 512, 0, stream>>>(QT, KT, St, sNN, sNN, sNN, 4, 16);
  // Att[b,m,d'] = sum_d V[b,m,d]*St[b,d',d]
  gemm_bt256<u16, false><<<256, 512, 0, stream>>>(V, St, Att, sNN, sNN, sNN, 4, 16);
  // out = Att @ Wr^T (fp32 epilogue)
  gemm_bt256<float, false><<<256, 512, 0, stream>>>(Att, Wrb, out, 0, 0, 0, 4, 256);
}

// Round 10
// 294.703 us; speedup vs baseline: 1.0850x; 1.0041x over previous
//
#include <hip/hip_runtime.h>

typedef unsigned short u16;
typedef unsigned int u32;
typedef __attribute__((ext_vector_type(4))) float f32x4;
typedef __attribute__((ext_vector_type(8))) short bf16x8;
typedef __attribute__((ext_vector_type(4))) u16 u16x4;
typedef __attribute__((ext_vector_type(8))) u16 u16x8;

#define B_ 16
#define N_ 1024
#define D_ 1024
#define BM 256
#define BN 256
#define BK 64

__device__ __forceinline__ float bf2f(u16 v) {
  return __uint_as_float((u32)v << 16);
}
__device__ __forceinline__ u16 f2bf(float f) {
  u32 u = __float_as_uint(f);
  return (u16)((u + 0x7FFFu + ((u >> 16) & 1u)) >> 16);
}
__device__ __forceinline__ void gload_lds16(const void* g, void* l) {
  __builtin_amdgcn_global_load_lds(
      (const __attribute__((address_space(1))) void*)g,
      (__attribute__((address_space(3))) void*)l, 16, 0, 0);
}

// ---------------- cast fp32 -> bf16 (vectorized) ----------------
__global__ __launch_bounds__(256) void cast_kernel(const float* __restrict__ in,
                                                   u16* __restrict__ out, int n4) {
  const int stride = gridDim.x * blockDim.x;
  for (int i = blockIdx.x * blockDim.x + threadIdx.x; i < n4; i += stride) {
    float4 v = ((const float4*)in)[i];
    u16x4 o;
    o[0] = f2bf(v.x); o[1] = f2bf(v.y); o[2] = f2bf(v.z); o[3] = f2bf(v.w);
    ((u16x4*)out)[i] = o;
  }
}

// fused cast of the 4 weight matrices into one contiguous bf16 region
__global__ __launch_bounds__(256) void cast4_kernel(
    const float* __restrict__ w0, const float* __restrict__ w1,
    const float* __restrict__ w2, const float* __restrict__ w3,
    u16* __restrict__ out) {
  const int per = (D_ * D_) / 4;
  const int stride = gridDim.x * blockDim.x;
  for (int i = blockIdx.x * blockDim.x + threadIdx.x; i < 4 * per; i += stride) {
    const int w = i / per, r = i - w * per;
    const float* src = (w == 0) ? w0 : (w == 1) ? w1 : (w == 2) ? w2 : w3;
    float4 v = ((const float4*)src)[r];
    u16x4 o;
    o[0] = f2bf(v.x); o[1] = f2bf(v.y); o[2] = f2bf(v.z); o[3] = f2bf(v.w);
    ((u16x4*)out)[i] = o;
  }
}

// ---------------- 256x256 8-wave bt-GEMM, 4 phases / 4 barriers per K-tile --
// C[i,j] = sum_k A[i,k]*B[j,k], K fixed = 1024 (16 K-tiles of BK=64).
// LDS: [region A0,A1,B0,B1 x 32KB][buf x 16KB] (region-major so that
// BUF*16384 + MI*2048 fits the 16-bit ds_read immediate).
// Swizzle byte^=((row&7)<<4). CRITICAL: the swizzle mask spans bits 4-6,
// so the kk half-select (64B) must be XOR-folded into the base, NEVER
// added: colswz(kk) = (kk*64 + kl*16) ^ ((rl&7)<<4), precomputed as two
// base pointers per operand (R7-R9 NaNs were `base + kk*64` carrying into
// bit 7 for lanes with rl&7 >= 4 -> wrong-row reads).
// Phase p = { ds_reads(p) [+ stage]; lgkmcnt(0); BAR; [stage]; 16 MFMA }.
// lgkmcnt(0) before each barrier => arrival guarantees this wave's reads
// are SAMPLED, so any post-barrier DMA write cannot clobber them.
// Gate vmcnt(4) once per tile in P4 (drains HA(t+1)+HB(t+1); leaves
// HB(t+2) in flight); tail vmcnt(0)@T=14, none @T=15.
template <typename OutT, bool SPLITC>
__global__ __launch_bounds__(512, 2) void gemm_bt256(
    const u16* __restrict__ A, const u16* __restrict__ Bm, OutT* __restrict__ C,
    long long sA, long long sB, long long sC, int tx_n, int nb_per) {
  __shared__ u16 lds[4][2][128 * 64];  // [A0,A1,B0,B1][buf]
  const int tid = threadIdx.x;
  const int lane = tid & 63;
  const int wid = tid >> 6;
  const int wm = wid >> 2;   // 0..1 -> 128-row half
  const int wn = wid & 3;    // 0..3 -> 64-col group
  const int rl = lane & 15, kl = lane >> 4;

  // bijective XCD swizzle (nwg % 8 == 0 for all our grids)
  const int nwg = gridDim.x;
  const int orig = blockIdx.x;
  const int wgid = (orig & 7) * (nwg >> 3) + (orig >> 3);
  const int batch = wgid / nb_per;
  const int rem = wgid % nb_per;
  const int row0 = (rem / tx_n) * BM;
  const int col0 = (rem % tx_n) * BN;
  A += (long long)batch * sA;
  Bm += (long long)batch * sB;
  OutT* Cb;
  if constexpr (SPLITC) {
    Cb = C + (size_t)(col0 >> 10) * ((size_t)16384 * 1024) + (col0 & 1023);
  } else {
    Cb = C + (long long)batch * sC + col0;
  }

  const char* lb = (const char*)&lds[0][0][0];
  char* lwt = (char*)&lds[0][0][0] + tid * 16;

  // kk-resolved swizzled read bases (XOR fold, see header comment)
  const u32 mask = (u32)((rl & 7) << 4);
  const u32 cs0 = ((u32)(kl * 16)) ^ mask;        // kk=0 column bytes
  const u32 cs1 = ((u32)(64 + kl * 16)) ^ mask;   // kk=1 column bytes
  const char* pAk0 = lb + wm * 32768 + rl * 128 + cs0;
  const char* pAk1 = lb + wm * 32768 + rl * 128 + cs1;
  const char* pBk0 =
      lb + (2 + (wn >> 1)) * 32768 + (wn & 1) * 8192 + rl * 128 + cs0;
  const char* pBk1 =
      lb + (2 + (wn >> 1)) * 32768 + (wn & 1) * 8192 + rl * 128 + cs1;
#define RDA(BUF, MI, KK) \
  (*(const bf16x8*)(((KK) ? pAk1 : pAk0) + (BUF)*16384 + (MI)*2048))
#define RDB(BUF, NI, KK) \
  (*(const bf16x8*)(((KK) ? pBk1 : pBk0) + (BUF)*16384 + (NI)*2048))

  // staging: linear LDS dest, inverse-swizzled global source
  const int r0 = tid >> 3;
  const u32 li0 = (u32)(((tid & 7) * 16) ^ ((r0 & 7) << 4));
  const u16* gA0 = A + (size_t)(row0 + r0) * 1024 + (li0 >> 1);
  const u16* gB0 = Bm + (size_t)(col0 + r0) * 1024 + (li0 >> 1);
#define STAGE_A(H, BUF, T)                                                    \
  do {                                                                        \
    gload_lds16(gA0 + (size_t)((H)*128 + 0) * 1024 + (T)*64,                  \
                lwt + (H)*32768 + (BUF)*16384);                               \
    gload_lds16(gA0 + (size_t)((H)*128 + 64) * 1024 + (T)*64,                 \
                lwt + (H)*32768 + (BUF)*16384 + 8192);                        \
  } while (0)
#define STAGE_B(H, BUF, T)                                                    \
  do {                                                                        \
    gload_lds16(gB0 + (size_t)((H)*128 + 0) * 1024 + (T)*64,                  \
                lwt + (2 + (H)) * 32768 + (BUF)*16384);                       \
    gload_lds16(gB0 + (size_t)((H)*128 + 64) * 1024 + (T)*64,                 \
                lwt + (2 + (H)) * 32768 + (BUF)*16384 + 8192);                \
  } while (0)

  f32x4 acc[8][4] = {};
  bf16x8 aF[4][2], bF[2][2], bG[2][2];

  auto mfma16 = [&](int rb, int cb, bf16x8 (&bb)[2][2]) {
#pragma unroll
    for (int kk = 0; kk < 2; ++kk)
#pragma unroll
      for (int mi = 0; mi < 4; ++mi)
#pragma unroll
        for (int ni = 0; ni < 2; ++ni)
          acc[rb + mi][cb + ni] = __builtin_amdgcn_mfma_f32_16x16x32_bf16(
              aF[mi][kk], bb[ni][kk], acc[rb + mi][cb + ni], 0, 0, 0);
  };

#define SBAR() __builtin_amdgcn_sched_barrier(0)
#define BAR() __builtin_amdgcn_s_barrier()
#define LGKM0() asm volatile("s_waitcnt lgkmcnt(0)" ::: "memory")
  // GATE: 0 = vmcnt(4)+bar, 1 = vmcnt(0)+bar, 2 = none
#define TILE(T, BUF, OBUF, STHA, STHB, GATE)                                  \
  {                                                                           \
    /* P1: reads A-sub0(8) + B-lo(4); stage HA0(T+1)->OBUF; MFMA Q00 */       \
    _Pragma("unroll") for (int mi = 0; mi < 4; ++mi) {                        \
      aF[mi][0] = RDA(BUF, mi, 0); aF[mi][1] = RDA(BUF, mi, 1);               \
    }                                                                         \
    _Pragma("unroll") for (int ni = 0; ni < 2; ++ni) {                        \
      bF[ni][0] = RDB(BUF, ni, 0); bF[ni][1] = RDB(BUF, ni, 1);               \
    }                                                                         \
    if (STHA) STAGE_A(0, OBUF, (T) + 1);                                      \
    LGKM0(); SBAR(); BAR(); SBAR();                                           \
    __builtin_amdgcn_s_setprio(1);                                            \
    mfma16(0, 0, bF);                                                         \
    __builtin_amdgcn_s_setprio(0);                                            \
    /* P2: reads B-hi(4); stage HA1(T+1)->OBUF; MFMA Q01 */                   \
    _Pragma("unroll") for (int ni = 0; ni < 2; ++ni) {                        \
      bG[ni][0] = RDB(BUF, 2 + ni, 0); bG[ni][1] = RDB(BUF, 2 + ni, 1);       \
    }                                                                         \
    if (STHA) STAGE_A(1, OBUF, (T) + 1);                                      \
    LGKM0(); SBAR(); BAR(); SBAR();                                           \
    __builtin_amdgcn_s_setprio(1);                                            \
    mfma16(0, 2, bG);                                                         \
    __builtin_amdgcn_s_setprio(0);                                            \
    /* P3: reads A-sub1(8); lgkm0; BAR; then stage HB0(T+2)->BUF; Q11 */      \
    _Pragma("unroll") for (int mi = 0; mi < 4; ++mi) {                        \
      aF[mi][0] = RDA(BUF, 4 + mi, 0); aF[mi][1] = RDA(BUF, 4 + mi, 1);       \
    }                                                                         \
    LGKM0(); SBAR(); BAR(); SBAR();                                           \
    if (STHB) STAGE_B(0, BUF, (T) + 2);                                       \
    SBAR();                                                                   \
    __builtin_amdgcn_s_setprio(1);                                            \
    mfma16(4, 2, bG);                                                         \
    __builtin_amdgcn_s_setprio(0);                                            \
    /* P4: stage HB1(T+2); counted gate; BAR; MFMA Q10 */                     \
    if (STHB) STAGE_B(1, BUF, (T) + 2);                                       \
    SBAR();                                                                   \
    if ((GATE) == 0) asm volatile("s_waitcnt vmcnt(4)" ::: "memory");         \
    else if ((GATE) == 1) asm volatile("s_waitcnt vmcnt(0)" ::: "memory");    \
    if ((GATE) != 2) BAR();                                                   \
    SBAR();                                                                   \
    __builtin_amdgcn_s_setprio(1);                                            \
    mfma16(4, 0, bF);                                                         \
    __builtin_amdgcn_s_setprio(0);                                            \
  }

  // prologue: A(0),B(0) -> buf0; B(1) -> buf1 (12 loads); gate first 8
  STAGE_A(0, 0, 0); STAGE_A(1, 0, 0);
  STAGE_B(0, 0, 0); STAGE_B(1, 0, 0);
  STAGE_B(0, 1, 1); STAGE_B(1, 1, 1);
  asm volatile("s_waitcnt vmcnt(4)" ::: "memory");
  BAR();

#pragma unroll 1
  for (int u = 0; u < 7; ++u) {
    TILE(2 * u, 0, 1, 1, 1, 0);
    TILE(2 * u + 1, 1, 0, 1, 1, 0);
  }
  TILE(14, 0, 1, 1, 0, 1);   // stage HA(15) only; drain to 0
  TILE(15, 1, 0, 0, 0, 2);   // final tile: no stages, no gate

#undef TILE
#undef SBAR
#undef BAR
#undef LGKM0
#undef RDA
#undef RDB
#undef STAGE_A
#undef STAGE_B

  // epilogue: C/D map col=lane&15, row=(lane>>4)*4+j
#pragma unroll
  for (int mi = 0; mi < 8; ++mi)
#pragma unroll
    for (int ni = 0; ni < 4; ++ni)
#pragma unroll
      for (int j = 0; j < 4; ++j) {
        const int rr = row0 + wm * 128 + mi * 16 + kl * 4 + j;
        const int cc = wn * 64 + ni * 16 + rl;
        const float v = acc[mi][ni][j];
        if constexpr (sizeof(OutT) == 2)
          Cb[(size_t)rr * 1024 + cc] = (OutT)f2bf(v);
        else
          Cb[(size_t)rr * 1024 + cc] = v;
      }
}

// ---------------- key: softmax over d (rows), write transposed KT[b,d,n] ----------------
__global__ __launch_bounds__(256) void key_sm_t(const u16* __restrict__ Kp,
                                                u16* __restrict__ KT) {
  const int b = blockIdx.y, n0 = blockIdx.x * 64;
  const int tid = threadIdx.x, lane = tid & 63, w = tid >> 6;
  __shared__ float smax[64], sinv[64];
  __shared__ u16 Tl[64][72];
  const u16* base = Kp + ((size_t)b * N_ + n0) * D_;
  for (int i = 0; i < 16; ++i) {
    const int r = w * 16 + i;
    const u16x8* rp = (const u16x8*)(base + (size_t)r * D_ + lane * 16);
    u16x8 v0 = rp[0], v1 = rp[1];
    float f[16];
#pragma unroll
    for (int j = 0; j < 8; ++j) { f[j] = bf2f(v0[j]); f[8 + j] = bf2f(v1[j]); }
    float m = -1e30f;
#pragma unroll
    for (int j = 0; j < 16; ++j) m = fmaxf(m, f[j]);
    for (int off = 32; off; off >>= 1) m = fmaxf(m, __shfl_xor(m, off));
    float s = 0.f;
#pragma unroll
    for (int j = 0; j < 16; ++j) s += __expf(f[j] - m);
    for (int off = 32; off; off >>= 1) s += __shfl_xor(s, off);
    if (lane == 0) { smax[r] = m; sinv[r] = 1.f / s; }
  }
  __syncthreads();
  for (int ct = 0; ct < 16; ++ct) {
    const int r = tid >> 2, cb = (tid & 3) * 16;
    const u16x8* rp = (const u16x8*)(base + (size_t)r * D_ + ct * 64 + cb);
    u16x8 v0 = rp[0], v1 = rp[1];
    const float m = smax[r], inv = sinv[r];
#pragma unroll
    for (int j = 0; j < 8; ++j) {
      Tl[r][cb + j] = f2bf(__expf(bf2f(v0[j]) - m) * inv);
      Tl[r][cb + 8 + j] = f2bf(__expf(bf2f(v1[j]) - m) * inv);
    }
    __syncthreads();
    const int c = tid >> 2, nb = (tid & 3) * 16;
    u16x8 o0, o1;
#pragma unroll
    for (int e = 0; e < 8; ++e) { o0[e] = Tl[nb + e][c]; o1[e] = Tl[nb + 8 + e][c]; }
    u16x8* op = (u16x8*)(KT + ((size_t)b * D_ + ct * 64 + c) * N_ + n0 + nb);
    op[0] = o0; op[1] = o1;
    __syncthreads();
  }
}

// ---------------- query: softmax over n (cols), write transposed QT[b,d,n] ----------------
// (round-6-proven version)
__global__ __launch_bounds__(256) void query_sm_t(const u16* __restrict__ Qp,
                                                  u16* __restrict__ QT) {
  const int b = blockIdx.y, d0 = blockIdx.x * 64;
  const int tid = threadIdx.x, l = tid & 63, g = tid >> 6;
  __shared__ float pm[4][64], ps[4][64];
  __shared__ float cmax[64], cinv[64];
  __shared__ u16 Tl[64][72];
  const u16* base = Qp + (size_t)b * N_ * D_;
  float m = -1e30f, s = 0.f;
  for (int n = g * 256; n < g * 256 + 256; ++n) {
    const float x = bf2f(base[(size_t)n * D_ + d0 + l]);
    const float nm = fmaxf(m, x);
    s = s * __expf(m - nm) + __expf(x - nm);
    m = nm;
  }
  pm[g][l] = m; ps[g][l] = s;
  __syncthreads();
  if (tid < 64) {
    float M = pm[0][tid];
    for (int k2 = 1; k2 < 4; ++k2) M = fmaxf(M, pm[k2][tid]);
    float S = 0.f;
    for (int k2 = 0; k2 < 4; ++k2) S += ps[k2][tid] * __expf(pm[k2][tid] - M);
    cmax[tid] = M; cinv[tid] = 1.f / S;
  }
  __syncthreads();
  for (int nt = 0; nt < 16; ++nt) {
    const int r = tid >> 2, cb = (tid & 3) * 16;
    const u16x8* rp = (const u16x8*)(base + (size_t)(nt * 64 + r) * D_ + d0 + cb);
    u16x8 v0 = rp[0], v1 = rp[1];
#pragma unroll
    for (int j = 0; j < 8; ++j) {
      Tl[r][cb + j] = f2bf(__expf(bf2f(v0[j]) - cmax[cb + j]) * cinv[cb + j]);
      Tl[r][cb + 8 + j] =
          f2bf(__expf(bf2f(v1[j]) - cmax[cb + 8 + j]) * cinv[cb + 8 + j]);
    }
    __syncthreads();
    const int c = tid >> 2, nb = (tid & 3) * 16;
    u16x8 o0, o1;
#pragma unroll
    for (int e = 0; e < 8; ++e) { o0[e] = Tl[nb + e][c]; o1[e] = Tl[nb + 8 + e][c]; }
    u16x8* op = (u16x8*)(QT + ((size_t)b * D_ + d0 + c) * N_ + nt * 64 + nb);
    op[0] = o0; op[1] = o1;
    __syncthreads();
  }
}

extern "C" void kernel_launch(void* const* d_in, const int* in_sizes, int n_in,
                              void* d_out, int out_size, void* d_ws, size_t ws_size,
                              hipStream_t stream) {
  const float* x = (const float*)d_in[0];
  const float* Wk = (const float*)d_in[1];
  const float* Wq = (const float*)d_in[2];
  const float* Wv = (const float*)d_in[3];
  const float* Wr = (const float*)d_in[4];
  float* out = (float*)d_out;
  char* ws = (char*)d_ws;
  const size_t MB = 1ull << 20;

  u16* Xb  = (u16*)(ws + 0 * MB);
  u16* KT  = (u16*)(ws + 0 * MB);
  u16* Wkb = (u16*)(ws + 32 * MB);   // [Wk;Wq;Wv;Wr] contiguous
  u16* Wrb = (u16*)(ws + 38 * MB);
  u16* Kp  = (u16*)(ws + 40 * MB);   // Kp/Qp/V each 32 MB apart (SPLITC routing)
  u16* St  = (u16*)(ws + 40 * MB);
  u16* Qp  = (u16*)(ws + 72 * MB);
  u16* Att = (u16*)(ws + 72 * MB);
  u16* V   = (u16*)(ws + 104 * MB);
  u16* QT  = (u16*)(ws + 136 * MB);

  const int nX = B_ * N_ * D_;
  cast_kernel<<<2048, 256, 0, stream>>>(x, Xb, nX / 4);
  cast4_kernel<<<1024, 256, 0, stream>>>(Wk, Wq, Wv, Wr, Wkb);

  // merged projections: (16384 x 3072) = Xb @ [Wk;Wq;Wv]^T -> 64x12 = 768 blocks
  gemm_bt256<u16, true><<<768, 512, 0, stream>>>(Xb, Wkb, Kp, 0, 0, 0, 12, 768);

  key_sm_t<<<dim3(N_ / 64, B_), 256, 0, stream>>>(Kp, KT);
  query_sm_t<<<dim3(D_ / 64, B_), 256, 0, stream>>>(Qp, QT);

  const long long sNN = (long long)N_ * D_;
  // St[b,d',d] = sum_n QT[b,d',n]*KT[b,d,n]: 16 batches x (4x4) = 256 blocks
  gemm_bt256<u16, false><<<256, 512, 0, stream>>>(QT, KT, St, sNN, sNN, sNN, 4, 16);
  // Att[b,m,d'] = sum_d V[b,m,d]*St[b,d',d]
  gemm_bt256<u16, false><<<256, 512, 0, stream>>>(V, St, Att, sNN, sNN, sNN, 4, 16);
  // out = Att @ Wr^T (fp32 epilogue)
  gemm_bt256<float, false><<<256, 512, 0, stream>>>(Att, Wrb, out, 0, 0, 0, 4, 256);
}

// Round 11
// 292.295 us; speedup vs baseline: 1.0939x; 1.0082x over previous
//
#include <hip/hip_runtime.h>

typedef unsigned short u16;
typedef unsigned int u32;
typedef __attribute__((ext_vector_type(4))) float f32x4;
typedef __attribute__((ext_vector_type(8))) short bf16x8;
typedef __attribute__((ext_vector_type(4))) u16 u16x4;
typedef __attribute__((ext_vector_type(8))) u16 u16x8;

#define B_ 16
#define N_ 1024
#define D_ 1024
#define BM 256
#define BN 256
#define BK 64

__device__ __forceinline__ float bf2f(u16 v) {
  return __uint_as_float((u32)v << 16);
}
__device__ __forceinline__ u16 f2bf(float f) {
  u32 u = __float_as_uint(f);
  return (u16)((u + 0x7FFFu + ((u >> 16) & 1u)) >> 16);
}
__device__ __forceinline__ void gload_lds16(const void* g, void* l) {
  __builtin_amdgcn_global_load_lds(
      (const __attribute__((address_space(1))) void*)g,
      (__attribute__((address_space(3))) void*)l, 16, 0, 0);
}

// ---------------- cast fp32 -> bf16 (vectorized) ----------------
__global__ __launch_bounds__(256) void cast_kernel(const float* __restrict__ in,
                                                   u16* __restrict__ out, int n4) {
  const int stride = gridDim.x * blockDim.x;
  for (int i = blockIdx.x * blockDim.x + threadIdx.x; i < n4; i += stride) {
    float4 v = ((const float4*)in)[i];
    u16x4 o;
    o[0] = f2bf(v.x); o[1] = f2bf(v.y); o[2] = f2bf(v.z); o[3] = f2bf(v.w);
    ((u16x4*)out)[i] = o;
  }
}

// fused cast of the 4 weight matrices into one contiguous bf16 region
__global__ __launch_bounds__(256) void cast4_kernel(
    const float* __restrict__ w0, const float* __restrict__ w1,
    const float* __restrict__ w2, const float* __restrict__ w3,
    u16* __restrict__ out) {
  const int per = (D_ * D_) / 4;
  const int stride = gridDim.x * blockDim.x;
  for (int i = blockIdx.x * blockDim.x + threadIdx.x; i < 4 * per; i += stride) {
    const int w = i / per, r = i - w * per;
    const float* src = (w == 0) ? w0 : (w == 1) ? w1 : (w == 2) ? w2 : w3;
    float4 v = ((const float4*)src)[r];
    u16x4 o;
    o[0] = f2bf(v.x); o[1] = f2bf(v.y); o[2] = f2bf(v.z); o[3] = f2bf(v.w);
    ((u16x4*)out)[i] = o;
  }
}

// ---------------- 256x256 8-wave bt-GEMM, 4 phases / 4 barriers per K-tile --
// C[i,j] = sum_k A[i,k]*B[j,k], K fixed = 1024 (16 K-tiles of BK=64).
// LDS: [region A0,A1,B0,B1 x 32KB][buf x 16KB]. Swizzle byte^=((row&7)<<4);
// kk half-select XOR-folded into precomputed base pointers (NEVER added —
// the R7-R9 NaN bug).
// R11 sync (m201 semantics): waves arrive at barriers with ds_reads in
// flight; `s_waitcnt lgkmcnt(0)` sits AFTER the barrier, before the MFMA
// cluster (sched_barrier(0) fences per rule #18). Overwrite ledger under
// this weaker guarantee (reads complete before consuming MFMA, which
// precedes arrival at the NEXT barrier):
//   HA0/HA1(t+1)->buf^1 in P1/P2 read-windows: A(buf^1) consumed by
//     Q11(t-1) < all arrivals at BAR4(t-1) < issuer passed it -> safe.
//   HB0/HB1(t+2)->buf issued AFTER BAR3: B reads complete before Q01
//     (lgkm0 post-BAR2) < all arrivals at BAR3 -> safe.
//   Q10 consumes registers only.
// Gate vmcnt(4) once per tile in P4 (drains HA(t+1)+HB(t+1); leaves
// HB(t+2) in flight); tail vmcnt(0)@T=14, none @T=15.
template <typename OutT, bool SPLITC>
__global__ __launch_bounds__(512, 2) void gemm_bt256(
    const u16* __restrict__ A, const u16* __restrict__ Bm, OutT* __restrict__ C,
    long long sA, long long sB, long long sC, int tx_n, int nb_per) {
  __shared__ u16 lds[4][2][128 * 64];  // [A0,A1,B0,B1][buf]
  const int tid = threadIdx.x;
  const int lane = tid & 63;
  const int wid = tid >> 6;
  const int wm = wid >> 2;   // 0..1 -> 128-row half
  const int wn = wid & 3;    // 0..3 -> 64-col group
  const int rl = lane & 15, kl = lane >> 4;

  // bijective XCD swizzle (nwg % 8 == 0 for all our grids)
  const int nwg = gridDim.x;
  const int orig = blockIdx.x;
  const int wgid = (orig & 7) * (nwg >> 3) + (orig >> 3);
  const int batch = wgid / nb_per;
  const int rem = wgid % nb_per;
  const int row0 = (rem / tx_n) * BM;
  const int col0 = (rem % tx_n) * BN;
  A += (long long)batch * sA;
  Bm += (long long)batch * sB;
  OutT* Cb;
  if constexpr (SPLITC) {
    Cb = C + (size_t)(col0 >> 10) * ((size_t)16384 * 1024) + (col0 & 1023);
  } else {
    Cb = C + (long long)batch * sC + col0;
  }

  const char* lb = (const char*)&lds[0][0][0];
  char* lwt = (char*)&lds[0][0][0] + tid * 16;

  // kk-resolved swizzled read bases (XOR fold, see header comment)
  const u32 mask = (u32)((rl & 7) << 4);
  const u32 cs0 = ((u32)(kl * 16)) ^ mask;        // kk=0 column bytes
  const u32 cs1 = ((u32)(64 + kl * 16)) ^ mask;   // kk=1 column bytes
  const char* pAk0 = lb + wm * 32768 + rl * 128 + cs0;
  const char* pAk1 = lb + wm * 32768 + rl * 128 + cs1;
  const char* pBk0 =
      lb + (2 + (wn >> 1)) * 32768 + (wn & 1) * 8192 + rl * 128 + cs0;
  const char* pBk1 =
      lb + (2 + (wn >> 1)) * 32768 + (wn & 1) * 8192 + rl * 128 + cs1;
#define RDA(BUF, MI, KK) \
  (*(const bf16x8*)(((KK) ? pAk1 : pAk0) + (BUF)*16384 + (MI)*2048))
#define RDB(BUF, NI, KK) \
  (*(const bf16x8*)(((KK) ? pBk1 : pBk0) + (BUF)*16384 + (NI)*2048))

  // staging: linear LDS dest, inverse-swizzled global source
  const int r0 = tid >> 3;
  const u32 li0 = (u32)(((tid & 7) * 16) ^ ((r0 & 7) << 4));
  const u16* gA0 = A + (size_t)(row0 + r0) * 1024 + (li0 >> 1);
  const u16* gB0 = Bm + (size_t)(col0 + r0) * 1024 + (li0 >> 1);
#define STAGE_A(H, BUF, T)                                                    \
  do {                                                                        \
    gload_lds16(gA0 + (size_t)((H)*128 + 0) * 1024 + (T)*64,                  \
                lwt + (H)*32768 + (BUF)*16384);                               \
    gload_lds16(gA0 + (size_t)((H)*128 + 64) * 1024 + (T)*64,                 \
                lwt + (H)*32768 + (BUF)*16384 + 8192);                        \
  } while (0)
#define STAGE_B(H, BUF, T)                                                    \
  do {                                                                        \
    gload_lds16(gB0 + (size_t)((H)*128 + 0) * 1024 + (T)*64,                  \
                lwt + (2 + (H)) * 32768 + (BUF)*16384);                       \
    gload_lds16(gB0 + (size_t)((H)*128 + 64) * 1024 + (T)*64,                 \
                lwt + (2 + (H)) * 32768 + (BUF)*16384 + 8192);                \
  } while (0)

  f32x4 acc[8][4] = {};
  bf16x8 aF[4][2], bF[2][2], bG[2][2];

  auto mfma16 = [&](int rb, int cb, bf16x8 (&bb)[2][2]) {
#pragma unroll
    for (int kk = 0; kk < 2; ++kk)
#pragma unroll
      for (int mi = 0; mi < 4; ++mi)
#pragma unroll
        for (int ni = 0; ni < 2; ++ni)
          acc[rb + mi][cb + ni] = __builtin_amdgcn_mfma_f32_16x16x32_bf16(
              aF[mi][kk], bb[ni][kk], acc[rb + mi][cb + ni], 0, 0, 0);
  };

#define SBAR() __builtin_amdgcn_sched_barrier(0)
#define BAR() __builtin_amdgcn_s_barrier()
#define LGKM0() asm volatile("s_waitcnt lgkmcnt(0)" ::: "memory")
#define LGKM8() asm volatile("s_waitcnt lgkmcnt(8)" ::: "memory")
  // GATE: 0 = vmcnt(4)+bar, 1 = vmcnt(0)+bar, 2 = none
#define TILE(T, BUF, OBUF, STHA, STHB, GATE)                                  \
  {                                                                           \
    /* P1: reads A-sub0(8)+B-lo(4); stage HA0(T+1)->OBUF; BAR; lgkm0; Q00 */  \
    _Pragma("unroll") for (int mi = 0; mi < 4; ++mi) {                        \
      aF[mi][0] = RDA(BUF, mi, 0); aF[mi][1] = RDA(BUF, mi, 1);               \
    }                                                                         \
    _Pragma("unroll") for (int ni = 0; ni < 2; ++ni) {                        \
      bF[ni][0] = RDB(BUF, ni, 0); bF[ni][1] = RDB(BUF, ni, 1);               \
    }                                                                         \
    if (STHA) STAGE_A(0, OBUF, (T) + 1);                                      \
    LGKM8(); SBAR(); BAR(); SBAR();                                           \
    LGKM0(); SBAR();                                                          \
    __builtin_amdgcn_s_setprio(1);                                            \
    mfma16(0, 0, bF);                                                         \
    __builtin_amdgcn_s_setprio(0);                                            \
    /* P2: reads B-hi(4); stage HA1(T+1)->OBUF; BAR; lgkm0; Q01 */            \
    _Pragma("unroll") for (int ni = 0; ni < 2; ++ni) {                        \
      bG[ni][0] = RDB(BUF, 2 + ni, 0); bG[ni][1] = RDB(BUF, 2 + ni, 1);       \
    }                                                                         \
    if (STHA) STAGE_A(1, OBUF, (T) + 1);                                      \
    SBAR(); BAR(); SBAR();                                                    \
    LGKM0(); SBAR();                                                          \
    __builtin_amdgcn_s_setprio(1);                                            \
    mfma16(0, 2, bG);                                                         \
    __builtin_amdgcn_s_setprio(0);                                            \
    /* P3: reads A-sub1(8); BAR; stage HB0(T+2)->BUF; lgkm0; Q11 */           \
    _Pragma("unroll") for (int mi = 0; mi < 4; ++mi) {                        \
      aF[mi][0] = RDA(BUF, 4 + mi, 0); aF[mi][1] = RDA(BUF, 4 + mi, 1);       \
    }                                                                         \
    SBAR(); BAR(); SBAR();                                                    \
    if (STHB) STAGE_B(0, BUF, (T) + 2);                                       \
    SBAR();                                                                   \
    LGKM0(); SBAR();                                                          \
    __builtin_amdgcn_s_setprio(1);                                            \
    mfma16(4, 2, bG);                                                         \
    __builtin_amdgcn_s_setprio(0);                                            \
    /* P4: stage HB1(T+2); counted gate; BAR; Q10 (registers only) */         \
    if (STHB) STAGE_B(1, BUF, (T) + 2);                                       \
    SBAR();                                                                   \
    if ((GATE) == 0) asm volatile("s_waitcnt vmcnt(4)" ::: "memory");         \
    else if ((GATE) == 1) asm volatile("s_waitcnt vmcnt(0)" ::: "memory");    \
    if ((GATE) != 2) BAR();                                                   \
    SBAR();                                                                   \
    __builtin_amdgcn_s_setprio(1);                                            \
    mfma16(4, 0, bF);                                                         \
    __builtin_amdgcn_s_setprio(0);                                            \
  }

  // prologue: A(0),B(0) -> buf0; B(1) -> buf1 (12 loads); gate first 8
  STAGE_A(0, 0, 0); STAGE_A(1, 0, 0);
  STAGE_B(0, 0, 0); STAGE_B(1, 0, 0);
  STAGE_B(0, 1, 1); STAGE_B(1, 1, 1);
  asm volatile("s_waitcnt vmcnt(4)" ::: "memory");
  BAR();

#pragma unroll 1
  for (int u = 0; u < 7; ++u) {
    TILE(2 * u, 0, 1, 1, 1, 0);
    TILE(2 * u + 1, 1, 0, 1, 1, 0);
  }
  TILE(14, 0, 1, 1, 0, 1);   // stage HA(15) only; drain to 0
  TILE(15, 1, 0, 0, 0, 2);   // final tile: no stages, no gate

#undef TILE
#undef SBAR
#undef BAR
#undef LGKM0
#undef LGKM8
#undef RDA
#undef RDB
#undef STAGE_A
#undef STAGE_B

  // epilogue: C/D map col=lane&15, row=(lane>>4)*4+j
#pragma unroll
  for (int mi = 0; mi < 8; ++mi)
#pragma unroll
    for (int ni = 0; ni < 4; ++ni)
#pragma unroll
      for (int j = 0; j < 4; ++j) {
        const int rr = row0 + wm * 128 + mi * 16 + kl * 4 + j;
        const int cc = wn * 64 + ni * 16 + rl;
        const float v = acc[mi][ni][j];
        if constexpr (sizeof(OutT) == 2)
          Cb[(size_t)rr * 1024 + cc] = (OutT)f2bf(v);
        else
          Cb[(size_t)rr * 1024 + cc] = v;
      }
}

// ---------------- key: softmax over d (rows), write transposed KT[b,d,n] ----------------
__global__ __launch_bounds__(256) void key_sm_t(const u16* __restrict__ Kp,
                                                u16* __restrict__ KT) {
  const int b = blockIdx.y, n0 = blockIdx.x * 64;
  const int tid = threadIdx.x, lane = tid & 63, w = tid >> 6;
  __shared__ float smax[64], sinv[64];
  __shared__ u16 Tl[64][72];
  const u16* base = Kp + ((size_t)b * N_ + n0) * D_;
  for (int i = 0; i < 16; ++i) {
    const int r = w * 16 + i;
    const u16x8* rp = (const u16x8*)(base + (size_t)r * D_ + lane * 16);
    u16x8 v0 = rp[0], v1 = rp[1];
    float f[16];
#pragma unroll
    for (int j = 0; j < 8; ++j) { f[j] = bf2f(v0[j]); f[8 + j] = bf2f(v1[j]); }
    float m = -1e30f;
#pragma unroll
    for (int j = 0; j < 16; ++j) m = fmaxf(m, f[j]);
    for (int off = 32; off; off >>= 1) m = fmaxf(m, __shfl_xor(m, off));
    float s = 0.f;
#pragma unroll
    for (int j = 0; j < 16; ++j) s += __expf(f[j] - m);
    for (int off = 32; off; off >>= 1) s += __shfl_xor(s, off);
    if (lane == 0) { smax[r] = m; sinv[r] = 1.f / s; }
  }
  __syncthreads();
  for (int ct = 0; ct < 16; ++ct) {
    const int r = tid >> 2, cb = (tid & 3) * 16;
    const u16x8* rp = (const u16x8*)(base + (size_t)r * D_ + ct * 64 + cb);
    u16x8 v0 = rp[0], v1 = rp[1];
    const float m = smax[r], inv = sinv[r];
#pragma unroll
    for (int j = 0; j < 8; ++j) {
      Tl[r][cb + j] = f2bf(__expf(bf2f(v0[j]) - m) * inv);
      Tl[r][cb + 8 + j] = f2bf(__expf(bf2f(v1[j]) - m) * inv);
    }
    __syncthreads();
    const int c = tid >> 2, nb = (tid & 3) * 16;
    u16x8 o0, o1;
#pragma unroll
    for (int e = 0; e < 8; ++e) { o0[e] = Tl[nb + e][c]; o1[e] = Tl[nb + 8 + e][c]; }
    u16x8* op = (u16x8*)(KT + ((size_t)b * D_ + ct * 64 + c) * N_ + n0 + nb);
    op[0] = o0; op[1] = o1;
    __syncthreads();
  }
}

// ---------------- query: softmax over n (cols), write transposed QT[b,d,n] ----------------
// (round-6-proven version)
__global__ __launch_bounds__(256) void query_sm_t(const u16* __restrict__ Qp,
                                                  u16* __restrict__ QT) {
  const int b = blockIdx.y, d0 = blockIdx.x * 64;
  const int tid = threadIdx.x, l = tid & 63, g = tid >> 6;
  __shared__ float pm[4][64], ps[4][64];
  __shared__ float cmax[64], cinv[64];
  __shared__ u16 Tl[64][72];
  const u16* base = Qp + (size_t)b * N_ * D_;
  float m = -1e30f, s = 0.f;
  for (int n = g * 256; n < g * 256 + 256; ++n) {
    const float x = bf2f(base[(size_t)n * D_ + d0 + l]);
    const float nm = fmaxf(m, x);
    s = s * __expf(m - nm) + __expf(x - nm);
    m = nm;
  }
  pm[g][l] = m; ps[g][l] = s;
  __syncthreads();
  if (tid < 64) {
    float M = pm[0][tid];
    for (int k2 = 1; k2 < 4; ++k2) M = fmaxf(M, pm[k2][tid]);
    float S = 0.f;
    for (int k2 = 0; k2 < 4; ++k2) S += ps[k2][tid] * __expf(pm[k2][tid] - M);
    cmax[tid] = M; cinv[tid] = 1.f / S;
  }
  __syncthreads();
  for (int nt = 0; nt < 16; ++nt) {
    const int r = tid >> 2, cb = (tid & 3) * 16;
    const u16x8* rp = (const u16x8*)(base + (size_t)(nt * 64 + r) * D_ + d0 + cb);
    u16x8 v0 = rp[0], v1 = rp[1];
#pragma unroll
    for (int j = 0; j < 8; ++j) {
      Tl[r][cb + j] = f2bf(__expf(bf2f(v0[j]) - cmax[cb + j]) * cinv[cb + j]);
      Tl[r][cb + 8 + j] =
          f2bf(__expf(bf2f(v1[j]) - cmax[cb + 8 + j]) * cinv[cb + 8 + j]);
    }
    __syncthreads();
    const int c = tid >> 2, nb = (tid & 3) * 16;
    u16x8 o0, o1;
#pragma unroll
    for (int e = 0; e < 8; ++e) { o0[e] = Tl[nb + e][c]; o1[e] = Tl[nb + 8 + e][c]; }
    u16x8* op = (u16x8*)(QT + ((size_t)b * D_ + d0 + c) * N_ + nt * 64 + nb);
    op[0] = o0; op[1] = o1;
    __syncthreads();
  }
}

extern "C" void kernel_launch(void* const* d_in, const int* in_sizes, int n_in,
                              void* d_out, int out_size, void* d_ws, size_t ws_size,
                              hipStream_t stream) {
  const float* x = (const float*)d_in[0];
  const float* Wk = (const float*)d_in[1];
  const float* Wq = (const float*)d_in[2];
  const float* Wv = (const float*)d_in[3];
  const float* Wr = (const float*)d_in[4];
  float* out = (float*)d_out;
  char* ws = (char*)d_ws;
  const size_t MB = 1ull << 20;

  u16* Xb  = (u16*)(ws + 0 * MB);
  u16* KT  = (u16*)(ws + 0 * MB);
  u16* Wkb = (u16*)(ws + 32 * MB);   // [Wk;Wq;Wv;Wr] contiguous
  u16* Wrb = (u16*)(ws + 38 * MB);
  u16* Kp  = (u16*)(ws + 40 * MB);   // Kp/Qp/V each 32 MB apart (SPLITC routing)
  u16* St  = (u16*)(ws + 40 * MB);
  u16* Qp  = (u16*)(ws + 72 * MB);
  u16* Att = (u16*)(ws + 72 * MB);
  u16* V   = (u16*)(ws + 104 * MB);
  u16* QT  = (u16*)(ws + 136 * MB);

  const int nX = B_ * N_ * D_;
  cast_kernel<<<2048, 256, 0, stream>>>(x, Xb, nX / 4);
  cast4_kernel<<<1024, 256, 0, stream>>>(Wk, Wq, Wv, Wr, Wkb);

  // merged projections: (16384 x 3072) = Xb @ [Wk;Wq;Wv]^T -> 64x12 = 768 blocks
  gemm_bt256<u16, true><<<768, 512, 0, stream>>>(Xb, Wkb, Kp, 0, 0, 0, 12, 768);

  key_sm_t<<<dim3(N_ / 64, B_), 256, 0, stream>>>(Kp, KT);
  query_sm_t<<<dim3(D_ / 64, B_), 256, 0, stream>>>(Qp, QT);

  const long long sNN = (long long)N_ * D_;
  // St[b,d',d] = sum_n QT[b,d',n]*KT[b,d,n]: 16 batches x (4x4) = 256 blocks
  gemm_bt256<u16, false><<<256, 512, 0, stream>>>(QT, KT, St, sNN, sNN, sNN, 4, 16);
  // Att[b,m,d'] = sum_d V[b,m,d]*St[b,d',d]
  gemm_bt256<u16, false><<<256, 512, 0, stream>>>(V, St, Att, sNN, sNN, sNN, 4, 16);
  // out = Att @ Wr^T (fp32 epilogue)
  gemm_bt256<float, false><<<256, 512, 0, stream>>>(Att, Wrb, out, 0, 0, 0, 4, 256);
}